// Round 15
// baseline (231.343 us; speedup 1.0000x reference)
//
#include <hip/hip_runtime.h>
#include <hip/hip_bf16.h>

#define B_  32
#define N_  8192
#define C1  64
#define C2  128
#define C3  256
#define KO  40

typedef __attribute__((ext_vector_type(8))) short bh8;
typedef __attribute__((ext_vector_type(4))) float f32x4;

union FragU { uint u[4]; bh8 h; uint4 v; };

#define MFMA_BF16 __builtin_amdgcn_mfma_f32_16x16x32_bf16

// ---------- helpers ----------

__device__ __forceinline__ float ftanh(float x) {
    float e = __expf(2.0f * x);
    float r = __builtin_amdgcn_rcpf(e + 1.0f);
    return fmaf(-2.0f, r, 1.0f);
}

__device__ __forceinline__ float waveMax(float v) {
    v = fmaxf(v, __shfl_xor(v, 32, 64));
    v = fmaxf(v, __shfl_xor(v, 16, 64));
    v = fmaxf(v, __shfl_xor(v, 8, 64));
    v = fmaxf(v, __shfl_xor(v, 4, 64));
    v = fmaxf(v, __shfl_xor(v, 2, 64));
    v = fmaxf(v, __shfl_xor(v, 1, 64));
    return v;
}
__device__ __forceinline__ float quadMax(float v) {  // reduce over ln=lane&15
    v = fmaxf(v, __shfl_xor(v, 1, 64));
    v = fmaxf(v, __shfl_xor(v, 2, 64));
    v = fmaxf(v, __shfl_xor(v, 4, 64));
    v = fmaxf(v, __shfl_xor(v, 8, 64));
    return v;
}

// packed f32x2 -> bf16x2 (v_cvt_pk_bf16_f32 on gfx950)
__device__ __forceinline__ unsigned packbf(float a, float b) {
    __hip_bfloat162 p = __float22bfloat162_rn(make_float2(a, b));
    unsigned u;
    __builtin_memcpy(&u, &p, 4);
    return u;
}

// build one 16x16x32 A-frag (A[m=lane&15][k=quad*8+j]) from row-major fp32
__device__ __forceinline__ bh8 mkfrag(const float* src) {
    float4 lo = *(const float4*)(src);
    float4 hi = *(const float4*)(src + 4);
    FragU fu;
    fu.u[0] = packbf(lo.x, lo.y);
    fu.u[1] = packbf(lo.z, lo.w);
    fu.u[2] = packbf(hi.x, hi.y);
    fu.u[3] = packbf(hi.z, hi.w);
    return fu.h;
}

// ---------- k_passD: 512 threads (8 waves), 2 x 128-pt tiles per block,
// 1024 blocks = 32 b x 32 chunks. Fully self-contained:
//   integrated scan (each block re-scans its batch's x; L2-resident) ->
//   beff prologue -> per tile [layer1 -> L2 MFMA (h2->LDS) -> L3 MFMA] ->
//   per-block partial maxes PLAIN-STORED to slots (no atomics, no zero-init).
// NOTE: plain __launch_bounds__(512) — a min-waves arg caps VGPRs below the
// live set -> scratch spill -> 172 MB HBM writes, +55% dur (measured R8).
// NOTE: NO cross-block counters/fences/atomics — agent-scope ordered RMW
// emits cache-maintenance ops and serialized the grid (measured R7/R13). ----------

__global__ __launch_bounds__(512) void k_passD(const float* __restrict__ x,
                                               const float* __restrict__ w1,
                                               const float* __restrict__ b1,
                                               const float* __restrict__ w2,
                                               const float* __restrict__ b2,
                                               const float* __restrict__ w3,
                                               float* __restrict__ mx3p,
                                               float* __restrict__ gencp) {
    __shared__ uint4 h1v[8][130];
    __shared__ uint2 h2u[32][130];
    __shared__ float w1s[192];
    __shared__ float beff1s[C1];
    __shared__ float m2s[C1];
    __shared__ float beff2s[C2];

    int b = blockIdx.x >> 5;
    int chunk = blockIdx.x & 31;   // 256 points = 2 tiles
    int t = threadIdx.x;
    int p = t & 127, hh = t >> 7;  // hh in 0..3
    int lane = t & 63, wv = t >> 6, qd = lane >> 4, ln = lane & 15;  // wv in 0..7

    if (t < 192) w1s[t] = w1[t];

    // ---- integrated scan: all 8192 points of batch b, 16 pts/thread ----
    // redC overlays h2u (dead until layer2): [wave][0..63]=ch max, [64..66]=coord max
    {
        float* redC = (float*)&h2u[0][0];
        const float* xs = x + (size_t)b * 3 * N_;
        float sx0[16], sx1[16], sx2[16];
#pragma unroll
        for (int i = 0; i < 16; ++i) {
            sx0[i] = xs[t + i * 512];
            sx1[i] = xs[N_ + t + i * 512];
            sx2[i] = xs[2 * N_ + t + i * 512];
        }
        float c0 = sx0[0], c1 = sx1[0], c2 = sx2[0];
#pragma unroll
        for (int i = 1; i < 16; ++i) {
            c0 = fmaxf(c0, sx0[i]);
            c1 = fmaxf(c1, sx1[i]);
            c2 = fmaxf(c2, sx2[i]);
        }
        c0 = waveMax(c0); c1 = waveMax(c1); c2 = waveMax(c2);
        if (lane == 0) {
            redC[wv * 68 + 64] = c0;
            redC[wv * 68 + 65] = c1;
            redC[wv * 68 + 66] = c2;
        }
        float myCh = -1e30f;
#pragma unroll
        for (int o = 0; o < C1; ++o) {
            float w0 = w1[o * 3 + 0], wa = w1[o * 3 + 1], wb = w1[o * 3 + 2];
            float m = -1e30f;
#pragma unroll
            for (int i = 0; i < 16; ++i)
                m = fmaxf(m, fmaf(sx0[i], w0, fmaf(sx1[i], wa, sx2[i] * wb)));
            m = waveMax(m);
            if (lane == o) myCh = m;
        }
        redC[wv * 68 + lane] = myCh;
    }
    __syncthreads();  // S: redC ready

    // weight fragments direct from global fp32 (L2-hot; scan regs now dead)
    bh8 wf2[2];
    bh8 wf3[2][4];
#pragma unroll
    for (int ks = 0; ks < 2; ++ks)
        wf2[ks] = mkfrag(w2 + (wv * 16 + ln) * C1 + ks * 32 + qd * 8);
#pragma unroll
    for (int mi = 0; mi < 2; ++mi)
#pragma unroll
        for (int ks = 0; ks < 4; ++ks)
            wf3[mi][ks] = mkfrag(w3 + ((2 * wv + mi) * 16 + ln) * C2 + ks * 32 + qd * 8);

    // ---- beff1/m2 from scan partials ----
    if (t < C1) {
        const float* redC = (const float*)&h2u[0][0];
        float mraw = -1e30f, s0 = -1e30f, s1 = -1e30f, s2 = -1e30f;
#pragma unroll
        for (int w = 0; w < 8; ++w) {
            mraw = fmaxf(mraw, redC[w * 68 + t]);
            s0 = fmaxf(s0, redC[w * 68 + 64]);
            s1 = fmaxf(s1, redC[w * 68 + 65]);
            s2 = fmaxf(s2, redC[w * 68 + 66]);
        }
        float be = b1[t] - s0 * w1[t * 3 + 0] - s1 * w1[t * 3 + 1]
                         - s2 * w1[t * 3 + 2];
        beff1s[t] = be;
        m2s[t] = ftanh(mraw + be);
    }
    __syncthreads();  // P: beff1s, m2s ready (redC dead)

    // beff2 (t<128) runs alongside tile 0 layer1
    if (t < C2) {
        float a = b2[t];
#pragma unroll 8
        for (int f = 0; f < C1; ++f) a -= m2s[f] * w2[t * C1 + f];
        beff2s[t] = a;
    }

    // both tiles' x coords (L2-hot after scan)
    const float* xbase = x + (size_t)b * 3 * N_ + chunk * 256 + p;
    float xq0[2], xq1[2], xq2[2];
#pragma unroll
    for (int tile = 0; tile < 2; ++tile) {
        xq0[tile] = xbase[tile * 128];
        xq1[tile] = xbase[N_ + tile * 128];
        xq2[tile] = xbase[2 * N_ + tile * 128];
    }

    float vmax2[4];
    float vmax3[2][4];
#pragma unroll
    for (int r = 0; r < 4; ++r) vmax2[r] = -1e30f;
#pragma unroll
    for (int mi = 0; mi < 2; ++mi)
#pragma unroll
        for (int r = 0; r < 4; ++r) vmax3[mi][r] = -1e30f;
    f32x4 bb2;
    bool haveBb2 = false;

    for (int tile = 0; tile < 2; ++tile) {
        float x0 = xq0[tile], x1 = xq1[tile], x2 = xq2[tile];
        // ---- layer 1: channels hh*16..+15 for point p ----
#pragma unroll
        for (int qq = 0; qq < 2; ++qq) {
            int c = hh * 16 + qq * 8;
            float v[8];
#pragma unroll
            for (int s = 0; s < 8; ++s) {
                float a = beff1s[c + s];
                a = fmaf(x0, w1s[(c + s) * 3 + 0], a);
                a = fmaf(x1, w1s[(c + s) * 3 + 1], a);
                a = fmaf(x2, w1s[(c + s) * 3 + 2], a);
                v[s] = ftanh(a);
            }
            uint4 pk;
            pk.x = packbf(v[0], v[1]);
            pk.y = packbf(v[2], v[3]);
            pk.z = packbf(v[4], v[5]);
            pk.w = packbf(v[6], v[7]);
            h1v[hh * 2 + qq][p] = pk;
        }
        __syncthreads();  // A: h1 (+ beff2s on tile 0) ready; prev h2u reads done

        if (!haveBb2) {
#pragma unroll
            for (int r = 0; r < 4; ++r)
                bb2[r] = beff2s[wv * 16 + qd * 4 + r];
            haveBb2 = true;
        }

        // ---- layer 2 MFMA: wave wv -> M-tile wv; bias in C; h2 -> LDS ----
        for (int nb = 0; nb < 8; ++nb) {
            int n = nb * 16 + ln;
            f32x4 acc = bb2;
#pragma unroll
            for (int ks = 0; ks < 2; ++ks) {
                FragU fb;
                fb.v = h1v[ks * 4 + qd][n];
                acc = MFMA_BF16(wf2[ks], fb.h, acc, 0, 0, 0);
            }
#pragma unroll
            for (int r = 0; r < 4; ++r)
                vmax2[r] = fmaxf(vmax2[r], acc[r]);
            h2u[wv * 4 + qd][n] = make_uint2(packbf(ftanh(acc[0]), ftanh(acc[1])),
                                            packbf(ftanh(acc[2]), ftanh(acc[3])));
        }
        __syncthreads();  // B: h2 ready (h1 consumed)

        // ---- layer 3 MFMA: wave wv -> M-tiles {2wv, 2wv+1}; max in regs ----
        for (int nb = 0; nb < 8; ++nb) {
            int n = nb * 16 + ln;
            f32x4 acc[2];
#pragma unroll
            for (int mi = 0; mi < 2; ++mi) acc[mi] = (f32x4){0.f, 0.f, 0.f, 0.f};
#pragma unroll
            for (int ks = 0; ks < 4; ++ks) {
                int kk = ks * 4 + qd;
                uint2 u0 = h2u[2 * kk][n], u1 = h2u[2 * kk + 1][n];
                FragU fb;
                fb.u[0] = u0.x; fb.u[1] = u0.y; fb.u[2] = u1.x; fb.u[3] = u1.y;
#pragma unroll
                for (int mi = 0; mi < 2; ++mi)
                    acc[mi] = MFMA_BF16(wf3[mi][ks], fb.h, acc[mi], 0, 0, 0);
            }
#pragma unroll
            for (int mi = 0; mi < 2; ++mi)
#pragma unroll
                for (int r = 0; r < 4; ++r)
                    vmax3[mi][r] = fmaxf(vmax3[mi][r], acc[mi][r]);
        }
        // no barrier: next tile's bar A fences the h2u reads
    }

    // ---- per-block partial maxes -> slots (plain stores; no atomics) ----
    int slot = chunk * 32 + b;
#pragma unroll
    for (int r = 0; r < 4; ++r) {
        float v = quadMax(vmax2[r]);
        if (ln == 0) mx3p[slot * C2 + wv * 16 + qd * 4 + r] = v;
    }
#pragma unroll
    for (int mi = 0; mi < 2; ++mi)
#pragma unroll
        for (int r = 0; r < 4; ++r) {
            float v = quadMax(vmax3[mi][r]);
            if (ln == 0) gencp[slot * C3 + (2 * wv + mi) * 16 + qd * 4 + r] = v;
        }
}

// ---------- k_fc: slot-reduce + beff3 inline + FC head + log_softmax ----------

__global__ __launch_bounds__(256) void k_fc(const float* __restrict__ mx3p,
                                            const float* __restrict__ gencp,
                                            const float* __restrict__ w3,
                                            const float* __restrict__ b3,
                                            const float* __restrict__ fc1w,
                                            const float* __restrict__ fc1b,
                                            const float* __restrict__ fc2w,
                                            const float* __restrict__ fc2b,
                                            float* __restrict__ out) {
    __shared__ float m3[C2];
    __shared__ float gs[C3];
    __shared__ float hs[C2];
    __shared__ float vs[KO];
    __shared__ float red[2];
    int b = blockIdx.x, t = threadIdx.x;
    if (t < C2) {
        float m = -1e30f;
#pragma unroll 8
        for (int c = 0; c < 32; ++c)
            m = fmaxf(m, mx3p[(c * 32 + b) * C2 + t]);
        m3[t] = ftanh(m);
    }
    __syncthreads();
    {   // slot-reduce g, beff3 inline, pooled feature
        float g = -1e30f;
#pragma unroll 8
        for (int c = 0; c < 32; ++c)
            g = fmaxf(g, gencp[(c * 32 + b) * C3 + t]);
        float a = b3[t];
#pragma unroll 8
        for (int f = 0; f < C2; ++f) a -= m3[f] * w3[t * C2 + f];
        gs[t] = ftanh(g + a);
    }
    __syncthreads();
    if (t < C2) {
        float a = fc1b[t];
#pragma unroll 8
        for (int i = 0; i < C3; ++i) a = fmaf(gs[i], fc1w[t * C3 + i], a);
        hs[t] = ftanh(a);
    }
    __syncthreads();
    if (t < KO) {
        float a = fc2b[t];
#pragma unroll 8
        for (int i = 0; i < C2; ++i) a = fmaf(hs[i], fc2w[t * C2 + i], a);
        vs[t] = ftanh(a);
    }
    __syncthreads();
    if (t == 0) {
        float m = -1e30f;
        for (int j = 0; j < KO; ++j) m = fmaxf(m, vs[j]);
        float s = 0.0f;
        for (int j = 0; j < KO; ++j) s += __expf(vs[j] - m);
        red[0] = m;
        red[1] = __logf(s);
    }
    __syncthreads();
    if (t < KO) out[b * KO + t] = vs[t] - red[0] - red[1];
}

// ---------- launcher: 2 dispatches, no memsets ----------

extern "C" void kernel_launch(void* const* d_in, const int* in_sizes, int n_in,
                              void* d_out, int out_size, void* d_ws, size_t ws_size,
                              hipStream_t stream) {
    const float* x    = (const float*)d_in[0];
    const float* w1   = (const float*)d_in[1];
    const float* b1   = (const float*)d_in[2];
    const float* w2   = (const float*)d_in[3];
    const float* b2   = (const float*)d_in[4];
    const float* w3   = (const float*)d_in[5];
    const float* b3   = (const float*)d_in[6];
    const float* fc1w = (const float*)d_in[7];
    const float* fc1b = (const float*)d_in[8];
    const float* fc2w = (const float*)d_in[9];
    const float* fc2b = (const float*)d_in[10];
    float* out = (float*)d_out;

    float* W = (float*)d_ws;
    // slot buffers, fully overwritten every call (no zero-init needed)
    float* gencp = W;             // 32 slots x 32 b x 256 ch = 262144 floats
    float* mx3p  = W + 262144;    // 32 slots x 32 b x 128 ch = 131072 floats

    k_passD<<<B_ * 32, 512, 0, stream>>>(x, w1, b1, w2, b2, w3, mx3p, gencp);
    k_fc<<<B_, 256, 0, stream>>>(mx3p, gencp, w3, b3, fc1w, fc1b, fc2w, fc2b, out);
}

// Round 16
// 136.782 us; speedup vs baseline: 1.6913x; 1.6913x over previous
//
#include <hip/hip_runtime.h>
#include <hip/hip_bf16.h>

#define B_  32
#define N_  8192
#define C1  64
#define C2  128
#define C3  256
#define KO  40
#define SLOTS 8

typedef __attribute__((ext_vector_type(8))) short bh8;
typedef __attribute__((ext_vector_type(4))) float f32x4;

union FragU { uint u[4]; bh8 h; uint4 v; };

#define MFMA_BF16 __builtin_amdgcn_mfma_f32_16x16x32_bf16

// ---------- helpers ----------

__device__ __forceinline__ float ftanh(float x) {
    float e = __expf(2.0f * x);
    float r = __builtin_amdgcn_rcpf(e + 1.0f);
    return fmaf(-2.0f, r, 1.0f);
}

__device__ __forceinline__ float quadMax(float v) {  // reduce over ln=lane&15
    v = fmaxf(v, __shfl_xor(v, 1, 64));
    v = fmaxf(v, __shfl_xor(v, 2, 64));
    v = fmaxf(v, __shfl_xor(v, 4, 64));
    v = fmaxf(v, __shfl_xor(v, 8, 64));
    return v;
}

// order-preserving float<->uint encoding; 0u is below every real encoding
__device__ __forceinline__ unsigned encf(float f) {
    unsigned u = __float_as_uint(f);
    return (u & 0x80000000u) ? ~u : (u | 0x80000000u);
}
__device__ __forceinline__ float decf(unsigned e) {
    return __uint_as_float((e & 0x80000000u) ? (e & 0x7fffffffu) : ~e);
}

// packed f32x2 -> bf16x2 (v_cvt_pk_bf16_f32 on gfx950)
__device__ __forceinline__ unsigned packbf(float a, float b) {
    __hip_bfloat162 p = __float22bfloat162_rn(make_float2(a, b));
    unsigned u;
    __builtin_memcpy(&u, &p, 4);
    return u;
}

// ---------- k_scan (128 threads/block):
//   blocks [0,256):   x scan -> per-slot coord max + layer1-preact max (no atomics)
//   blocks [256,296): weight prep fp32 -> bf16 MFMA A-fragments
//   blocks [296,298): zero genc | mx3e ----------

__global__ __launch_bounds__(128) void k_scan(const float* __restrict__ x,
                                              const float* __restrict__ w1,
                                              const float* __restrict__ w2,
                                              const float* __restrict__ w3,
                                              float* __restrict__ mx1p,
                                              float* __restrict__ mx2p,
                                              uint4* __restrict__ w2f,
                                              uint4* __restrict__ w3f,
                                              unsigned* __restrict__ zeroBase) {
    int t = threadIdx.x;
    int bid = blockIdx.x;
    if (bid < 256) {
        int b = bid >> 3, s = bid & 7;
        const float* xb = x + (size_t)b * 3 * N_ + s * 1024 + t;
        float x0[8], x1[8], x2[8];
#pragma unroll
        for (int i = 0; i < 8; ++i) {
            x0[i] = xb[i * 128];
            x1[i] = xb[N_ + i * 128];
            x2[i] = xb[2 * N_ + i * 128];
        }
        float c0 = x0[0], c1 = x1[0], c2 = x2[0];
#pragma unroll
        for (int i = 1; i < 8; ++i) {
            c0 = fmaxf(c0, x0[i]);
            c1 = fmaxf(c1, x1[i]);
            c2 = fmaxf(c2, x2[i]);
        }
        __shared__ float tl[67][132];  // 132 cols: float4-aligned row stride
#pragma unroll
        for (int o = 0; o < C1; ++o) {
            float w0 = w1[o * 3 + 0], wa = w1[o * 3 + 1], wb = w1[o * 3 + 2];
            float m = -1e30f;
#pragma unroll
            for (int i = 0; i < 8; ++i)
                m = fmaxf(m, fmaf(x0[i], w0, fmaf(x1[i], wa, x2[i] * wb)));
            tl[o][t] = m;
        }
        tl[64][t] = c0;
        tl[65][t] = c1;
        tl[66][t] = c2;
        __syncthreads();
        if (t < 67) {
            const float4* row = (const float4*)&tl[t][0];
            float4 a0 = row[0], a1 = row[1], a2 = row[2], a3 = row[3];
#pragma unroll
            for (int j = 4; j < 32; j += 4) {
                float4 r0 = row[j], r1 = row[j + 1], r2 = row[j + 2], r3 = row[j + 3];
                a0.x = fmaxf(a0.x, r0.x); a0.y = fmaxf(a0.y, r0.y);
                a0.z = fmaxf(a0.z, r0.z); a0.w = fmaxf(a0.w, r0.w);
                a1.x = fmaxf(a1.x, r1.x); a1.y = fmaxf(a1.y, r1.y);
                a1.z = fmaxf(a1.z, r1.z); a1.w = fmaxf(a1.w, r1.w);
                a2.x = fmaxf(a2.x, r2.x); a2.y = fmaxf(a2.y, r2.y);
                a2.z = fmaxf(a2.z, r2.z); a2.w = fmaxf(a2.w, r2.w);
                a3.x = fmaxf(a3.x, r3.x); a3.y = fmaxf(a3.y, r3.y);
                a3.z = fmaxf(a3.z, r3.z); a3.w = fmaxf(a3.w, r3.w);
            }
            float m = fmaxf(fmaxf(fmaxf(a0.x, a0.y), fmaxf(a0.z, a0.w)),
                            fmaxf(fmaxf(a1.x, a1.y), fmaxf(a1.z, a1.w)));
            m = fmaxf(m, fmaxf(fmaxf(a2.x, a2.y), fmaxf(a2.z, a2.w)));
            m = fmaxf(m, fmaxf(fmaxf(a3.x, a3.y), fmaxf(a3.z, a3.w)));
            if (t < 64) mx2p[(s * 32 + b) * 64 + t] = m;
            else        mx1p[(s * 32 + b) * 4 + (t - 64)] = m;
        }
    } else if (bid < 296) {
        // weight prep (16x16x32 A-frag layout: A[m=lane&15][k=quad*8+j])
        int tid = (bid - 256) * 128 + t;  // 0..5119
        const float* src;
        uint4* dst;
        if (tid < 1024) {  // W2: 8 Mt x 2 ks x 64 lanes
            int lane = tid & 63, ks = (tid >> 6) & 1, mt = tid >> 7;
            src = w2 + (mt * 16 + (lane & 15)) * C1 + ks * 32 + (lane >> 4) * 8;
            dst = w2f + tid;
        } else {           // W3: 16 Mt x 4 ks x 64 lanes
            int fj = tid - 1024;
            int lane = fj & 63, ks = (fj >> 6) & 3, mt = fj >> 8;
            src = w3 + (mt * 16 + (lane & 15)) * C2 + ks * 32 + (lane >> 4) * 8;
            dst = w3f + fj;
        }
        uint4 o;
        o.x = packbf(src[0], src[1]);
        o.y = packbf(src[2], src[3]);
        o.z = packbf(src[4], src[5]);
        o.w = packbf(src[6], src[7]);
        *dst = o;
    } else {
        int idx = (bid - 296) * 128 + t;
        for (int i = idx; i < 8192 + 4096; i += 256) zeroBase[i] = 0u;
    }
}

// ---------- k_passD: 512 threads (8 waves), 4 x 128-pt tiles per block,
// 512 blocks = 32 b x 16 chunks (exactly 2 blocks/CU co-resident).
// Prologue (1 barrier) -> per tile: [layer1 -> barA -> L2 MFMA (+mx3 in regs,
// h2->LDS) -> barB -> L3 MFMA]; maxes flushed once per block at the end.
// NOTE: plain __launch_bounds__(512). A min-waves arg caps VGPRs below the
// live set -> scratch spill -> 172 MB HBM writes, +55% dur (measured R8).
// NOTE: NO cross-block counters/fences — per-block agent-scope ordered RMW
// costs cache-maintenance ops and serialized the grid (measured R7/R13).
// NOTE: NO integrated scan — 32x-redundant scan saturates VALU (measured R15). ----------

__global__ __launch_bounds__(512) void k_passD(const float* __restrict__ x,
                                               const float* __restrict__ w1,
                                               const float* __restrict__ b1,
                                               const float* __restrict__ w2,
                                               const float* __restrict__ b2,
                                               const float* __restrict__ mx1p,
                                               const float* __restrict__ mx2p,
                                               const uint4* __restrict__ w2f,
                                               const uint4* __restrict__ w3f,
                                               unsigned* __restrict__ mx3e,
                                               unsigned* __restrict__ genc) {
    __shared__ uint4 h1v[8][130];
    __shared__ uint2 h2u[32][130];
    __shared__ float w1s[192];
    __shared__ float beff1s[C1];
    __shared__ float m2s[C1];
    __shared__ float beff2s[C2];

    int b = blockIdx.x >> 4;
    int chunk = blockIdx.x & 15;   // 512 points = 4 tiles
    int t = threadIdx.x;
    int p = t & 127, hh = t >> 7;  // hh in 0..3
    int lane = t & 63, wv = t >> 6, qd = lane >> 4, ln = lane & 15;  // wv in 0..7

    // all 4 tiles' x coords issued early (latency hidden under prologue)
    const float* xbase = x + (size_t)b * 3 * N_ + chunk * 512 + p;
    float xq0[4], xq1[4], xq2[4];
#pragma unroll
    for (int tile = 0; tile < 4; ++tile) {
        xq0[tile] = xbase[tile * 128];
        xq1[tile] = xbase[N_ + tile * 128];
        xq2[tile] = xbase[2 * N_ + tile * 128];
    }

    // ---- prologue (single barrier): sm via block-uniform loads ----
    if (t < 192) w1s[t] = w1[t];
    if (t < C1) {
        float mraw = -1e30f;
#pragma unroll
        for (int s = 0; s < SLOTS; ++s)
            mraw = fmaxf(mraw, mx2p[(s * 32 + b) * 64 + t]);
        float s0 = -1e30f, s1 = -1e30f, s2 = -1e30f;
#pragma unroll
        for (int s = 0; s < SLOTS; ++s) {  // block-uniform -> s_load broadcast
            s0 = fmaxf(s0, mx1p[(s * 32 + b) * 4 + 0]);
            s1 = fmaxf(s1, mx1p[(s * 32 + b) * 4 + 1]);
            s2 = fmaxf(s2, mx1p[(s * 32 + b) * 4 + 2]);
        }
        float be = b1[t] - s0 * w1[t * 3 + 0] - s1 * w1[t * 3 + 1]
                         - s2 * w1[t * 3 + 2];
        beff1s[t] = be;
        m2s[t] = ftanh(mraw + be);
    }
    // weight fragments once per block (amortized over all 4 tiles)
    bh8 wf2[2];
    bh8 wf3[2][4];
#pragma unroll
    for (int ks = 0; ks < 2; ++ks) {
        FragU fu;
        fu.v = w2f[(wv * 2 + ks) * 64 + lane];
        wf2[ks] = fu.h;
    }
#pragma unroll
    for (int mi = 0; mi < 2; ++mi)
#pragma unroll
        for (int ks = 0; ks < 4; ++ks) {
            FragU fu;
            fu.v = w3f[((2 * wv + mi) * 4 + ks) * 64 + lane];
            wf3[mi][ks] = fu.h;
        }
    __syncthreads();  // P: w1s, beff1s, m2s ready

    // beff2 (t<128) runs alongside tile 0 layer1
    if (t < C2) {
        float a = b2[t];
#pragma unroll 8
        for (int f = 0; f < C1; ++f) a -= m2s[f] * w2[t * C1 + f];
        beff2s[t] = a;
    }

    float vmax2[4];
    float vmax3[2][4];
#pragma unroll
    for (int r = 0; r < 4; ++r) vmax2[r] = -1e30f;
#pragma unroll
    for (int mi = 0; mi < 2; ++mi)
#pragma unroll
        for (int r = 0; r < 4; ++r) vmax3[mi][r] = -1e30f;
    f32x4 bb2;
    bool haveBb2 = false;

    for (int tile = 0; tile < 4; ++tile) {
        float x0 = xq0[tile], x1 = xq1[tile], x2 = xq2[tile];
        // ---- layer 1: channels hh*16..+15 for point p ----
#pragma unroll
        for (int qq = 0; qq < 2; ++qq) {
            int c = hh * 16 + qq * 8;
            float v[8];
#pragma unroll
            for (int s = 0; s < 8; ++s) {
                float a = beff1s[c + s];
                a = fmaf(x0, w1s[(c + s) * 3 + 0], a);
                a = fmaf(x1, w1s[(c + s) * 3 + 1], a);
                a = fmaf(x2, w1s[(c + s) * 3 + 2], a);
                v[s] = ftanh(a);
            }
            uint4 pk;
            pk.x = packbf(v[0], v[1]);
            pk.y = packbf(v[2], v[3]);
            pk.z = packbf(v[4], v[5]);
            pk.w = packbf(v[6], v[7]);
            h1v[hh * 2 + qq][p] = pk;
        }
        __syncthreads();  // A: h1 (+ beff2s on tile 0) ready; prev h2u reads done

        if (!haveBb2) {
#pragma unroll
            for (int r = 0; r < 4; ++r)
                bb2[r] = beff2s[wv * 16 + qd * 4 + r];
            haveBb2 = true;
        }

        // ---- layer 2 MFMA: wave wv -> M-tile wv; bias in C; h2 -> LDS ----
        for (int nb = 0; nb < 8; ++nb) {
            int n = nb * 16 + ln;
            f32x4 acc = bb2;
#pragma unroll
            for (int ks = 0; ks < 2; ++ks) {
                FragU fb;
                fb.v = h1v[ks * 4 + qd][n];
                acc = MFMA_BF16(wf2[ks], fb.h, acc, 0, 0, 0);
            }
#pragma unroll
            for (int r = 0; r < 4; ++r)
                vmax2[r] = fmaxf(vmax2[r], acc[r]);
            h2u[wv * 4 + qd][n] = make_uint2(packbf(ftanh(acc[0]), ftanh(acc[1])),
                                            packbf(ftanh(acc[2]), ftanh(acc[3])));
        }
        __syncthreads();  // B: h2 ready (h1 consumed)

        // ---- layer 3 MFMA: wave wv -> M-tiles {2wv, 2wv+1}; max in regs ----
        for (int nb = 0; nb < 8; ++nb) {
            int n = nb * 16 + ln;
            f32x4 acc[2];
#pragma unroll
            for (int mi = 0; mi < 2; ++mi) acc[mi] = (f32x4){0.f, 0.f, 0.f, 0.f};
#pragma unroll
            for (int ks = 0; ks < 4; ++ks) {
                int kk = ks * 4 + qd;
                uint2 u0 = h2u[2 * kk][n], u1 = h2u[2 * kk + 1][n];
                FragU fb;
                fb.u[0] = u0.x; fb.u[1] = u0.y; fb.u[2] = u1.x; fb.u[3] = u1.y;
#pragma unroll
                for (int mi = 0; mi < 2; ++mi)
                    acc[mi] = MFMA_BF16(wf3[mi][ks], fb.h, acc[mi], 0, 0, 0);
            }
#pragma unroll
            for (int mi = 0; mi < 2; ++mi)
#pragma unroll
                for (int r = 0; r < 4; ++r)
                    vmax3[mi][r] = fmaxf(vmax3[mi][r], acc[mi][r]);
        }
        // no barrier: next tile's bar A fences the h2u reads
    }

    // ---- pooled maxes -> global (once per block) ----
#pragma unroll
    for (int r = 0; r < 4; ++r) {
        float v = quadMax(vmax2[r]);
        if (ln == 0)
            atomicMax(&mx3e[b * C2 + wv * 16 + qd * 4 + r], encf(v));
    }
#pragma unroll
    for (int mi = 0; mi < 2; ++mi)
#pragma unroll
        for (int r = 0; r < 4; ++r) {
            float v = quadMax(vmax3[mi][r]);
            if (ln == 0)
                atomicMax(&genc[b * C3 + (2 * wv + mi) * 16 + qd * 4 + r], encf(v));
        }
}

// ---------- k_fc: beff3 inline + FC head + log_softmax ----------

__global__ __launch_bounds__(256) void k_fc(const unsigned* __restrict__ mx3e,
                                            const unsigned* __restrict__ genc,
                                            const float* __restrict__ w3,
                                            const float* __restrict__ b3,
                                            const float* __restrict__ fc1w,
                                            const float* __restrict__ fc1b,
                                            const float* __restrict__ fc2w,
                                            const float* __restrict__ fc2b,
                                            float* __restrict__ out) {
    __shared__ float m3[C2];
    __shared__ float gs[C3];
    __shared__ float hs[C2];
    __shared__ float vs[KO];
    __shared__ float red[2];
    int b = blockIdx.x, t = threadIdx.x;
    if (t < C2) m3[t] = ftanh(decf(mx3e[b * C2 + t]));
    __syncthreads();
    {   // beff3 inline, then pooled feature
        float a = b3[t];
#pragma unroll 8
        for (int f = 0; f < C2; ++f) a -= m3[f] * w3[t * C2 + f];
        gs[t] = ftanh(decf(genc[b * C3 + t]) + a);
    }
    __syncthreads();
    if (t < C2) {
        float a = fc1b[t];
#pragma unroll 8
        for (int i = 0; i < C3; ++i) a = fmaf(gs[i], fc1w[t * C3 + i], a);
        hs[t] = ftanh(a);
    }
    __syncthreads();
    if (t < KO) {
        float a = fc2b[t];
#pragma unroll 8
        for (int i = 0; i < C2; ++i) a = fmaf(hs[i], fc2w[t * C2 + i], a);
        vs[t] = ftanh(a);
    }
    __syncthreads();
    if (t == 0) {
        float m = -1e30f;
        for (int j = 0; j < KO; ++j) m = fmaxf(m, vs[j]);
        float s = 0.0f;
        for (int j = 0; j < KO; ++j) s += __expf(vs[j] - m);
        red[0] = m;
        red[1] = __logf(s);
    }
    __syncthreads();
    if (t < KO) out[b * KO + t] = vs[t] - red[0] - red[1];
}

// ---------- launcher ----------

extern "C" void kernel_launch(void* const* d_in, const int* in_sizes, int n_in,
                              void* d_out, int out_size, void* d_ws, size_t ws_size,
                              hipStream_t stream) {
    const float* x    = (const float*)d_in[0];
    const float* w1   = (const float*)d_in[1];
    const float* b1   = (const float*)d_in[2];
    const float* w2   = (const float*)d_in[3];
    const float* b2   = (const float*)d_in[4];
    const float* w3   = (const float*)d_in[5];
    const float* b3   = (const float*)d_in[6];
    const float* fc1w = (const float*)d_in[7];
    const float* fc1b = (const float*)d_in[8];
    const float* fc2w = (const float*)d_in[9];
    const float* fc2b = (const float*)d_in[10];
    float* out = (float*)d_out;

    float* W = (float*)d_ws;
    // word offsets; [genc|mx3e] zeroed inside k_scan
    unsigned* genc = (unsigned*)W;             // 8192
    unsigned* mx3e = (unsigned*)(W + 8192);    // 4096
    float*    mx1p = W + 12288;                // 1024  [s*32+b]*4+c
    float*    mx2p = W + 13312;                // 16384 [s*32+b]*64+o
    uint4*    w2f  = (uint4*)(W + 29696);      // 4096 words
    uint4*    w3f  = (uint4*)(W + 33792);      // 16384 words

    k_scan<<<298, 128, 0, stream>>>(x, w1, w2, w3, mx1p, mx2p, w2f, w3f, genc);
    k_passD<<<B_ * 16, 512, 0, stream>>>(x, w1, b1, w2, b2,
                                         mx1p, mx2p, w2f, w3f, mx3e, genc);
    k_fc<<<B_, 256, 0, stream>>>(mx3e, genc, w3, b3, fc1w, fc1b, fc2w, fc2b, out);
}

// Round 17
// 134.232 us; speedup vs baseline: 1.7234x; 1.0190x over previous
//
#include <hip/hip_runtime.h>
#include <hip/hip_bf16.h>

#define B_  32
#define N_  8192
#define C1  64
#define C2  128
#define C3  256
#define KO  40
#define SLOTS 8

typedef __attribute__((ext_vector_type(8))) short bh8;
typedef __attribute__((ext_vector_type(4))) float f32x4;

union FragU { uint u[4]; bh8 h; uint4 v; };

#define MFMA_BF16 __builtin_amdgcn_mfma_f32_16x16x32_bf16

// ---------- helpers ----------

__device__ __forceinline__ float ftanh(float x) {
    float e = __expf(2.0f * x);
    float r = __builtin_amdgcn_rcpf(e + 1.0f);
    return fmaf(-2.0f, r, 1.0f);
}

__device__ __forceinline__ float quadMax(float v) {  // reduce over ln=lane&15
    v = fmaxf(v, __shfl_xor(v, 1, 64));
    v = fmaxf(v, __shfl_xor(v, 2, 64));
    v = fmaxf(v, __shfl_xor(v, 4, 64));
    v = fmaxf(v, __shfl_xor(v, 8, 64));
    return v;
}

// order-preserving float<->uint encoding; 0u is below every real encoding
__device__ __forceinline__ unsigned encf(float f) {
    unsigned u = __float_as_uint(f);
    return (u & 0x80000000u) ? ~u : (u | 0x80000000u);
}
__device__ __forceinline__ float decf(unsigned e) {
    return __uint_as_float((e & 0x80000000u) ? (e & 0x7fffffffu) : ~e);
}

// packed f32x2 -> bf16x2 (v_cvt_pk_bf16_f32 on gfx950)
__device__ __forceinline__ unsigned packbf(float a, float b) {
    __hip_bfloat162 p = __float22bfloat162_rn(make_float2(a, b));
    unsigned u;
    __builtin_memcpy(&u, &p, 4);
    return u;
}

// ---------- k_scan (128 threads/block):
//   blocks [0,256):   x scan -> per-slot coord max + layer1-preact max (no atomics)
//   blocks [256,296): weight prep fp32 -> bf16 MFMA A-fragments
//   blocks [296,298): zero genc | mx3e ----------

__global__ __launch_bounds__(128) void k_scan(const float* __restrict__ x,
                                              const float* __restrict__ w1,
                                              const float* __restrict__ w2,
                                              const float* __restrict__ w3,
                                              float* __restrict__ mx1p,
                                              float* __restrict__ mx2p,
                                              uint4* __restrict__ w2f,
                                              uint4* __restrict__ w3f,
                                              unsigned* __restrict__ zeroBase) {
    int t = threadIdx.x;
    int bid = blockIdx.x;
    if (bid < 256) {
        int b = bid >> 3, s = bid & 7;
        const float* xb = x + (size_t)b * 3 * N_ + s * 1024 + t;
        float x0[8], x1[8], x2[8];
#pragma unroll
        for (int i = 0; i < 8; ++i) {
            x0[i] = xb[i * 128];
            x1[i] = xb[N_ + i * 128];
            x2[i] = xb[2 * N_ + i * 128];
        }
        float c0 = x0[0], c1 = x1[0], c2 = x2[0];
#pragma unroll
        for (int i = 1; i < 8; ++i) {
            c0 = fmaxf(c0, x0[i]);
            c1 = fmaxf(c1, x1[i]);
            c2 = fmaxf(c2, x2[i]);
        }
        __shared__ float tl[67][132];  // 132 cols: float4-aligned row stride
#pragma unroll
        for (int o = 0; o < C1; ++o) {
            float w0 = w1[o * 3 + 0], wa = w1[o * 3 + 1], wb = w1[o * 3 + 2];
            float m = -1e30f;
#pragma unroll
            for (int i = 0; i < 8; ++i)
                m = fmaxf(m, fmaf(x0[i], w0, fmaf(x1[i], wa, x2[i] * wb)));
            tl[o][t] = m;
        }
        tl[64][t] = c0;
        tl[65][t] = c1;
        tl[66][t] = c2;
        __syncthreads();
        if (t < 67) {
            const float4* row = (const float4*)&tl[t][0];
            float4 a0 = row[0], a1 = row[1], a2 = row[2], a3 = row[3];
#pragma unroll
            for (int j = 4; j < 32; j += 4) {
                float4 r0 = row[j], r1 = row[j + 1], r2 = row[j + 2], r3 = row[j + 3];
                a0.x = fmaxf(a0.x, r0.x); a0.y = fmaxf(a0.y, r0.y);
                a0.z = fmaxf(a0.z, r0.z); a0.w = fmaxf(a0.w, r0.w);
                a1.x = fmaxf(a1.x, r1.x); a1.y = fmaxf(a1.y, r1.y);
                a1.z = fmaxf(a1.z, r1.z); a1.w = fmaxf(a1.w, r1.w);
                a2.x = fmaxf(a2.x, r2.x); a2.y = fmaxf(a2.y, r2.y);
                a2.z = fmaxf(a2.z, r2.z); a2.w = fmaxf(a2.w, r2.w);
                a3.x = fmaxf(a3.x, r3.x); a3.y = fmaxf(a3.y, r3.y);
                a3.z = fmaxf(a3.z, r3.z); a3.w = fmaxf(a3.w, r3.w);
            }
            float m = fmaxf(fmaxf(fmaxf(a0.x, a0.y), fmaxf(a0.z, a0.w)),
                            fmaxf(fmaxf(a1.x, a1.y), fmaxf(a1.z, a1.w)));
            m = fmaxf(m, fmaxf(fmaxf(a2.x, a2.y), fmaxf(a2.z, a2.w)));
            m = fmaxf(m, fmaxf(fmaxf(a3.x, a3.y), fmaxf(a3.z, a3.w)));
            if (t < 64) mx2p[(s * 32 + b) * 64 + t] = m;
            else        mx1p[(s * 32 + b) * 4 + (t - 64)] = m;
        }
    } else if (bid < 296) {
        // weight prep (16x16x32 A-frag layout: A[m=lane&15][k=quad*8+j])
        int tid = (bid - 256) * 128 + t;  // 0..5119
        const float* src;
        uint4* dst;
        if (tid < 1024) {  // W2: 8 Mt x 2 ks x 64 lanes
            int lane = tid & 63, ks = (tid >> 6) & 1, mt = tid >> 7;
            src = w2 + (mt * 16 + (lane & 15)) * C1 + ks * 32 + (lane >> 4) * 8;
            dst = w2f + tid;
        } else {           // W3: 16 Mt x 4 ks x 64 lanes
            int fj = tid - 1024;
            int lane = fj & 63, ks = (fj >> 6) & 3, mt = fj >> 8;
            src = w3 + (mt * 16 + (lane & 15)) * C2 + ks * 32 + (lane >> 4) * 8;
            dst = w3f + fj;
        }
        uint4 o;
        o.x = packbf(src[0], src[1]);
        o.y = packbf(src[2], src[3]);
        o.z = packbf(src[4], src[5]);
        o.w = packbf(src[6], src[7]);
        *dst = o;
    } else {
        int idx = (bid - 296) * 128 + t;
        for (int i = idx; i < 8192 + 4096; i += 256) zeroBase[i] = 0u;
    }
}

// ---------- k_passD: 512 threads (8 waves), 8 x 128-pt tiles per block,
// 256 blocks = 32 b x 8 chunks (exactly 1 block/CU).
// Prologue (1 barrier) -> per tile: [layer1 -> barA -> L2 MFMA (+mx3 in regs,
// h2->LDS) -> barB -> L3 MFMA]; maxes flushed once per block at the end.
// NOTE: plain __launch_bounds__(512). A min-waves arg caps VGPRs below the
// live set -> scratch spill -> 172 MB HBM writes, +55% dur (measured R8).
// NOTE: NO cross-block counters/fences — per-block agent-scope ordered RMW
// costs cache-maintenance ops and serialized the grid (measured R7/R13).
// NOTE: NO integrated scan — 32x-redundant scan saturates VALU (measured R15). ----------

__global__ __launch_bounds__(512) void k_passD(const float* __restrict__ x,
                                               const float* __restrict__ w1,
                                               const float* __restrict__ b1,
                                               const float* __restrict__ w2,
                                               const float* __restrict__ b2,
                                               const float* __restrict__ mx1p,
                                               const float* __restrict__ mx2p,
                                               const uint4* __restrict__ w2f,
                                               const uint4* __restrict__ w3f,
                                               unsigned* __restrict__ mx3e,
                                               unsigned* __restrict__ genc) {
    __shared__ uint4 h1v[8][130];
    __shared__ uint2 h2u[32][130];
    __shared__ float w1s[192];
    __shared__ float beff1s[C1];
    __shared__ float m2s[C1];
    __shared__ float beff2s[C2];

    int b = blockIdx.x >> 3;
    int chunk = blockIdx.x & 7;    // 1024 points = 8 tiles
    int t = threadIdx.x;
    int p = t & 127, hh = t >> 7;  // hh in 0..3
    int lane = t & 63, wv = t >> 6, qd = lane >> 4, ln = lane & 15;  // wv in 0..7

    // all 8 tiles' x coords issued early (latency hidden under prologue)
    const float* xbase = x + (size_t)b * 3 * N_ + chunk * 1024 + p;
    float xq0[8], xq1[8], xq2[8];
#pragma unroll
    for (int tile = 0; tile < 8; ++tile) {
        xq0[tile] = xbase[tile * 128];
        xq1[tile] = xbase[N_ + tile * 128];
        xq2[tile] = xbase[2 * N_ + tile * 128];
    }

    // ---- prologue (single barrier): sm via block-uniform loads ----
    if (t < 192) w1s[t] = w1[t];
    if (t < C1) {
        float mraw = -1e30f;
#pragma unroll
        for (int s = 0; s < SLOTS; ++s)
            mraw = fmaxf(mraw, mx2p[(s * 32 + b) * 64 + t]);
        float s0 = -1e30f, s1 = -1e30f, s2 = -1e30f;
#pragma unroll
        for (int s = 0; s < SLOTS; ++s) {  // block-uniform -> s_load broadcast
            s0 = fmaxf(s0, mx1p[(s * 32 + b) * 4 + 0]);
            s1 = fmaxf(s1, mx1p[(s * 32 + b) * 4 + 1]);
            s2 = fmaxf(s2, mx1p[(s * 32 + b) * 4 + 2]);
        }
        float be = b1[t] - s0 * w1[t * 3 + 0] - s1 * w1[t * 3 + 1]
                         - s2 * w1[t * 3 + 2];
        beff1s[t] = be;
        m2s[t] = ftanh(mraw + be);
    }
    // weight fragments once per block (amortized over all 8 tiles)
    bh8 wf2[2];
    bh8 wf3[2][4];
#pragma unroll
    for (int ks = 0; ks < 2; ++ks) {
        FragU fu;
        fu.v = w2f[(wv * 2 + ks) * 64 + lane];
        wf2[ks] = fu.h;
    }
#pragma unroll
    for (int mi = 0; mi < 2; ++mi)
#pragma unroll
        for (int ks = 0; ks < 4; ++ks) {
            FragU fu;
            fu.v = w3f[((2 * wv + mi) * 4 + ks) * 64 + lane];
            wf3[mi][ks] = fu.h;
        }
    __syncthreads();  // P: w1s, beff1s, m2s ready

    // beff2 (t<128) runs alongside tile 0 layer1
    if (t < C2) {
        float a = b2[t];
#pragma unroll 8
        for (int f = 0; f < C1; ++f) a -= m2s[f] * w2[t * C1 + f];
        beff2s[t] = a;
    }

    float vmax2[4];
    float vmax3[2][4];
#pragma unroll
    for (int r = 0; r < 4; ++r) vmax2[r] = -1e30f;
#pragma unroll
    for (int mi = 0; mi < 2; ++mi)
#pragma unroll
        for (int r = 0; r < 4; ++r) vmax3[mi][r] = -1e30f;
    f32x4 bb2;
    bool haveBb2 = false;

    for (int tile = 0; tile < 8; ++tile) {
        float x0 = xq0[tile], x1 = xq1[tile], x2 = xq2[tile];
        // ---- layer 1: channels hh*16..+15 for point p ----
#pragma unroll
        for (int qq = 0; qq < 2; ++qq) {
            int c = hh * 16 + qq * 8;
            float v[8];
#pragma unroll
            for (int s = 0; s < 8; ++s) {
                float a = beff1s[c + s];
                a = fmaf(x0, w1s[(c + s) * 3 + 0], a);
                a = fmaf(x1, w1s[(c + s) * 3 + 1], a);
                a = fmaf(x2, w1s[(c + s) * 3 + 2], a);
                v[s] = ftanh(a);
            }
            uint4 pk;
            pk.x = packbf(v[0], v[1]);
            pk.y = packbf(v[2], v[3]);
            pk.z = packbf(v[4], v[5]);
            pk.w = packbf(v[6], v[7]);
            h1v[hh * 2 + qq][p] = pk;
        }
        __syncthreads();  // A: h1 (+ beff2s on tile 0) ready; prev h2u reads done

        if (!haveBb2) {
#pragma unroll
            for (int r = 0; r < 4; ++r)
                bb2[r] = beff2s[wv * 16 + qd * 4 + r];
            haveBb2 = true;
        }

        // ---- layer 2 MFMA: wave wv -> M-tile wv; bias in C; h2 -> LDS ----
        for (int nb = 0; nb < 8; ++nb) {
            int n = nb * 16 + ln;
            f32x4 acc = bb2;
#pragma unroll
            for (int ks = 0; ks < 2; ++ks) {
                FragU fb;
                fb.v = h1v[ks * 4 + qd][n];
                acc = MFMA_BF16(wf2[ks], fb.h, acc, 0, 0, 0);
            }
#pragma unroll
            for (int r = 0; r < 4; ++r)
                vmax2[r] = fmaxf(vmax2[r], acc[r]);
            h2u[wv * 4 + qd][n] = make_uint2(packbf(ftanh(acc[0]), ftanh(acc[1])),
                                            packbf(ftanh(acc[2]), ftanh(acc[3])));
        }
        __syncthreads();  // B: h2 ready (h1 consumed)

        // ---- layer 3 MFMA: wave wv -> M-tiles {2wv, 2wv+1}; max in regs ----
        for (int nb = 0; nb < 8; ++nb) {
            int n = nb * 16 + ln;
            f32x4 acc[2];
#pragma unroll
            for (int mi = 0; mi < 2; ++mi) acc[mi] = (f32x4){0.f, 0.f, 0.f, 0.f};
#pragma unroll
            for (int ks = 0; ks < 4; ++ks) {
                int kk = ks * 4 + qd;
                uint2 u0 = h2u[2 * kk][n], u1 = h2u[2 * kk + 1][n];
                FragU fb;
                fb.u[0] = u0.x; fb.u[1] = u0.y; fb.u[2] = u1.x; fb.u[3] = u1.y;
#pragma unroll
                for (int mi = 0; mi < 2; ++mi)
                    acc[mi] = MFMA_BF16(wf3[mi][ks], fb.h, acc[mi], 0, 0, 0);
            }
#pragma unroll
            for (int mi = 0; mi < 2; ++mi)
#pragma unroll
                for (int r = 0; r < 4; ++r)
                    vmax3[mi][r] = fmaxf(vmax3[mi][r], acc[mi][r]);
        }
        // no barrier: next tile's bar A fences the h2u reads
    }

    // ---- pooled maxes -> global (once per block) ----
#pragma unroll
    for (int r = 0; r < 4; ++r) {
        float v = quadMax(vmax2[r]);
        if (ln == 0)
            atomicMax(&mx3e[b * C2 + wv * 16 + qd * 4 + r], encf(v));
    }
#pragma unroll
    for (int mi = 0; mi < 2; ++mi)
#pragma unroll
        for (int r = 0; r < 4; ++r) {
            float v = quadMax(vmax3[mi][r]);
            if (ln == 0)
                atomicMax(&genc[b * C3 + (2 * wv + mi) * 16 + qd * 4 + r], encf(v));
        }
}

// ---------- k_fc: beff3 inline + FC head + log_softmax ----------

__global__ __launch_bounds__(256) void k_fc(const unsigned* __restrict__ mx3e,
                                            const unsigned* __restrict__ genc,
                                            const float* __restrict__ w3,
                                            const float* __restrict__ b3,
                                            const float* __restrict__ fc1w,
                                            const float* __restrict__ fc1b,
                                            const float* __restrict__ fc2w,
                                            const float* __restrict__ fc2b,
                                            float* __restrict__ out) {
    __shared__ float m3[C2];
    __shared__ float gs[C3];
    __shared__ float hs[C2];
    __shared__ float vs[KO];
    __shared__ float red[2];
    int b = blockIdx.x, t = threadIdx.x;
    if (t < C2) m3[t] = ftanh(decf(mx3e[b * C2 + t]));
    __syncthreads();
    {   // beff3 inline, then pooled feature
        float a = b3[t];
#pragma unroll 8
        for (int f = 0; f < C2; ++f) a -= m3[f] * w3[t * C2 + f];
        gs[t] = ftanh(decf(genc[b * C3 + t]) + a);
    }
    __syncthreads();
    if (t < C2) {
        float a = fc1b[t];
#pragma unroll 8
        for (int i = 0; i < C3; ++i) a = fmaf(gs[i], fc1w[t * C3 + i], a);
        hs[t] = ftanh(a);
    }
    __syncthreads();
    if (t < KO) {
        float a = fc2b[t];
#pragma unroll 8
        for (int i = 0; i < C2; ++i) a = fmaf(hs[i], fc2w[t * C2 + i], a);
        vs[t] = ftanh(a);
    }
    __syncthreads();
    if (t == 0) {
        float m = -1e30f;
        for (int j = 0; j < KO; ++j) m = fmaxf(m, vs[j]);
        float s = 0.0f;
        for (int j = 0; j < KO; ++j) s += __expf(vs[j] - m);
        red[0] = m;
        red[1] = __logf(s);
    }
    __syncthreads();
    if (t < KO) out[b * KO + t] = vs[t] - red[0] - red[1];
}

// ---------- launcher ----------

extern "C" void kernel_launch(void* const* d_in, const int* in_sizes, int n_in,
                              void* d_out, int out_size, void* d_ws, size_t ws_size,
                              hipStream_t stream) {
    const float* x    = (const float*)d_in[0];
    const float* w1   = (const float*)d_in[1];
    const float* b1   = (const float*)d_in[2];
    const float* w2   = (const float*)d_in[3];
    const float* b2   = (const float*)d_in[4];
    const float* w3   = (const float*)d_in[5];
    const float* b3   = (const float*)d_in[6];
    const float* fc1w = (const float*)d_in[7];
    const float* fc1b = (const float*)d_in[8];
    const float* fc2w = (const float*)d_in[9];
    const float* fc2b = (const float*)d_in[10];
    float* out = (float*)d_out;

    float* W = (float*)d_ws;
    // word offsets; [genc|mx3e] zeroed inside k_scan
    unsigned* genc = (unsigned*)W;             // 8192
    unsigned* mx3e = (unsigned*)(W + 8192);    // 4096
    float*    mx1p = W + 12288;                // 1024  [s*32+b]*4+c
    float*    mx2p = W + 13312;                // 16384 [s*32+b]*64+o
    uint4*    w2f  = (uint4*)(W + 29696);      // 4096 words
    uint4*    w3f  = (uint4*)(W + 33792);      // 16384 words

    k_scan<<<298, 128, 0, stream>>>(x, w1, w2, w3, mx1p, mx2p, w2f, w3f, genc);
    k_passD<<<B_ * 8, 512, 0, stream>>>(x, w1, b1, w2, b2,
                                        mx1p, mx2p, w2f, w3f, mx3e, genc);
    k_fc<<<B_, 256, 0, stream>>>(mx3e, genc, w3, b3, fc1w, fc1b, fc2w, fc2b, out);
}